// Round 2
// baseline (874.991 us; speedup 1.0000x reference)
//
#include <hip/hip_runtime.h>
#include <stdint.h>

#define T_TOK 8192   // B*S
#define HDIM  1024
#define FDIM  4096
#define NEXP  8
#define BM 128
#define BN 128
#define BK 64
#define RCAP 17408   // 2*T_TOK + NEXP*128 padding

typedef short  short8  __attribute__((ext_vector_type(8)));
typedef unsigned short ushort8 __attribute__((ext_vector_type(8)));
typedef float  f32x4   __attribute__((ext_vector_type(4)));

__device__ __forceinline__ unsigned short f2bf(float f) {
  unsigned u = __float_as_uint(f);
  u += 0x7fffu + ((u >> 16) & 1u);   // RNE
  return (unsigned short)(u >> 16);
}

__device__ __forceinline__ void gload16(const unsigned short* g, unsigned short* l) {
  __builtin_amdgcn_global_load_lds(
      (const __attribute__((address_space(1))) void*)g,
      (__attribute__((address_space(3))) void*)l, 16, 0, 0);
}

// ---------------- x -> bf16 ----------------
__global__ void k_convert_x(const float* __restrict__ x, unsigned short* __restrict__ xb) {
  int i = (blockIdx.x * 256 + threadIdx.x) * 4;
  float4 v = *(const float4*)(x + i);
  ushort4 o;
  o.x = f2bf(v.x); o.y = f2bf(v.y); o.z = f2bf(v.z); o.w = f2bf(v.w);
  *(ushort4*)(xb + i) = o;
}

// ---------------- weight transpose+convert: in [K][N] f32 -> out [N][K] bf16 ----------------
__global__ __launch_bounds__(256) void k_transp_cvt(const float* __restrict__ in,
                                                    unsigned short* __restrict__ out,
                                                    int K, int N) {
  __shared__ unsigned short s[64][72];   // pad: 144B row stride
  const float* ine = in + (size_t)blockIdx.z * K * N;
  unsigned short* oute = out + (size_t)blockIdx.z * K * N;
  int k0 = blockIdx.y * 64, n0 = blockIdx.x * 64;
  int t = threadIdx.x;
  int kr = t >> 4, nc = (t & 15) * 4;
#pragma unroll
  for (int it = 0; it < 4; ++it) {
    int k = it * 16 + kr;
    float4 v = *(const float4*)(ine + (size_t)(k0 + k) * N + n0 + nc);
    ushort4 u = make_ushort4(f2bf(v.x), f2bf(v.y), f2bf(v.z), f2bf(v.w));
    *(ushort4*)(&s[k][nc]) = u;
  }
  __syncthreads();
  int nr = t >> 3, kc = (t & 7) * 8;
#pragma unroll
  for (int v = 0; v < 2; ++v) {
    int n = v * 32 + nr;
    ushort8 o;
#pragma unroll
    for (int j = 0; j < 8; ++j) o[j] = s[kc + j][n];
    *(ushort8*)(oute + (size_t)(n0 + n) * K + k0 + kc) = o;
  }
}

// ---------------- gating: fp32 logits, softmax, top-2 ----------------
__global__ void k_gate(const float* __restrict__ x, const float* __restrict__ gw,
                       int2* __restrict__ eidx, float2* __restrict__ ewt) {
  int tid = threadIdx.x;
  int lane = tid & 63;
  int t = blockIdx.x * 4 + (tid >> 6);
  const float* xr = x + (size_t)t * HDIM;
  float acc[NEXP];
#pragma unroll
  for (int e = 0; e < NEXP; e++) acc[e] = 0.f;
#pragma unroll
  for (int i = 0; i < HDIM / 64; i++) {
    float xv = xr[i * 64 + lane];
#pragma unroll
    for (int e = 0; e < NEXP; e++) acc[e] += xv * gw[e * HDIM + i * 64 + lane];
  }
#pragma unroll
  for (int e = 0; e < NEXP; e++) {
    acc[e] += __shfl_xor(acc[e], 32);
    acc[e] += __shfl_xor(acc[e], 16);
    acc[e] += __shfl_xor(acc[e], 8);
    acc[e] += __shfl_xor(acc[e], 4);
    acc[e] += __shfl_xor(acc[e], 2);
    acc[e] += __shfl_xor(acc[e], 1);
  }
  float m = acc[0];
#pragma unroll
  for (int e = 1; e < NEXP; e++) m = fmaxf(m, acc[e]);
  float p[NEXP]; float s = 0.f;
#pragma unroll
  for (int e = 0; e < NEXP; e++) { p[e] = expf(acc[e] - m); s += p[e]; }
  float inv = 1.f / s;
#pragma unroll
  for (int e = 0; e < NEXP; e++) p[e] *= inv;
  int b0 = 0; float v0 = p[0];
#pragma unroll
  for (int e = 1; e < NEXP; e++) if (p[e] > v0) { v0 = p[e]; b0 = e; }
  int b1i = (b0 == 0) ? 1 : 0; float v1 = p[b1i];
#pragma unroll
  for (int e = 0; e < NEXP; e++) if (e != b0 && p[e] > v1) { v1 = p[e]; b1i = e; }
  if (lane == 0) { eidx[t] = make_int2(b0, b1i); ewt[t] = make_float2(v0, v1); }
}

// ---------------- deterministic per-expert compaction ----------------
__global__ void k_compact(const int2* __restrict__ eidx, const float2* __restrict__ ewt,
                          int* __restrict__ list_tok, float* __restrict__ list_wt,
                          int* __restrict__ counts) {
  int e = blockIdx.x;
  int tid = threadIdx.x, lane = tid & 63, wid = tid >> 6;
  __shared__ int sbase;
  __shared__ int wcnt[4];
  if (tid == 0) sbase = 0;
  __syncthreads();
  for (int c = 0; c < T_TOK; c += 256) {
    int t = c + tid;
    int2 ei = eidx[t];
    bool sel = (ei.x == e) || (ei.y == e);
    unsigned long long b = __ballot(sel);
    if (lane == 0) wcnt[wid] = __popcll(b);
    __syncthreads();
    int pre = sbase;
    for (int w = 0; w < wid; w++) pre += wcnt[w];
    int pos = pre + __popcll(b & ((1ull << lane) - 1ull));
    if (sel) {
      list_tok[e * T_TOK + pos] = t;
      float2 wv = ewt[t];
      list_wt[e * T_TOK + pos] = (ei.x == e) ? wv.x : wv.y;
    }
    __syncthreads();
    if (tid == 0) sbase += wcnt[0] + wcnt[1] + wcnt[2] + wcnt[3];
    __syncthreads();
  }
  if (tid == 0) counts[e] = sbase;
}

__global__ void k_offsets(const int* __restrict__ counts, int* __restrict__ off_pad) {
  if (threadIdx.x == 0) {
    int o = 0;
    off_pad[0] = 0;
    for (int e = 0; e < NEXP; e++) {
      o += ((counts[e] + BM - 1) / BM) * BM;
      off_pad[e + 1] = o;
    }
  }
}

// ---------------- GEMM1: h = silu(gather(x) @ w1[e] + b1[e]) ----------------
// A = gathered x rows [128 m][64 k], B = w1t rows [128 f][64 k] (w1t: [E][F][H] bf16)
__global__ __launch_bounds__(256) void k_gemm1(
    const unsigned short* __restrict__ xb, const unsigned short* __restrict__ w1t,
    const float* __restrict__ b1, const int* __restrict__ list_tok,
    const int* __restrict__ counts, const int* __restrict__ off_pad,
    unsigned short* __restrict__ h) {
  __shared__ __align__(16) unsigned short smem[2 * BM * BK];
  unsigned short* As = smem;
  unsigned short* Bs = smem + BM * BK;

  int r0 = blockIdx.y * BM;
  if (r0 >= off_pad[NEXP]) return;
  int e = 0;
#pragma unroll
  for (int i = 0; i < NEXP; ++i) if (r0 >= off_pad[i + 1]) e = i + 1;
  int base = off_pad[e], cnt = counts[e];
  int n0 = blockIdx.x * BN;

  int t = threadIdx.x, l = t & 63, w = t >> 6;
  int wm = w >> 1, wn = w & 1;

  const unsigned short* ag[4];
  const unsigned short* bg[4];
  unsigned short* al[4];
  unsigned short* bl[4];
#pragma unroll
  for (int s = 0; s < 4; ++s) {
    int rl = w * 32 + s * 8 + (l >> 3);
    int se = r0 - base + rl;
    int tok = (se < cnt) ? list_tok[e * T_TOK + se] : 0;
    ag[s] = xb + (size_t)tok * HDIM + (l & 7) * 8;
    al[s] = As + (w * 32 + s * 8) * BK;
    int nl = n0 + rl;
    bg[s] = w1t + (size_t)e * FDIM * HDIM + (size_t)nl * HDIM + (l & 7) * 8;
    bl[s] = Bs + (w * 32 + s * 8) * BK;
  }

  f32x4 acc[4][4];
#pragma unroll
  for (int m = 0; m < 4; ++m)
#pragma unroll
    for (int n = 0; n < 4; ++n) acc[m][n] = (f32x4){0.f, 0.f, 0.f, 0.f};

  for (int kt = 0; kt < HDIM / BK; ++kt) {
    __syncthreads();
#pragma unroll
    for (int s = 0; s < 4; ++s) {
      gload16(ag[s] + kt * BK, al[s]);
      gload16(bg[s] + kt * BK, bl[s]);
    }
    __syncthreads();
#pragma unroll
    for (int kh = 0; kh < 2; ++kh) {
      short8 af[4], bf[4];
#pragma unroll
      for (int m = 0; m < 4; ++m)
        af[m] = *(const short8*)(As + (wm * 64 + m * 16 + (l & 15)) * BK + kh * 32 + (l >> 4) * 8);
#pragma unroll
      for (int n = 0; n < 4; ++n)
        bf[n] = *(const short8*)(Bs + (wn * 64 + n * 16 + (l & 15)) * BK + kh * 32 + (l >> 4) * 8);
#pragma unroll
      for (int m = 0; m < 4; ++m)
#pragma unroll
        for (int n = 0; n < 4; ++n)
          acc[m][n] = __builtin_amdgcn_mfma_f32_16x16x32_bf16(af[m], bf[n], acc[m][n], 0, 0, 0);
    }
  }

  // epilogue: bias + silu -> bf16, LDS bounce for coalesced 16B stores
  __syncthreads();
  const float* b1e = b1 + (size_t)e * FDIM + n0;
  unsigned short* Cs = smem;   // 128x128 ushort = 32KB (reuse As+Bs)
#pragma unroll
  for (int m = 0; m < 4; ++m) {
    int row = wm * 64 + m * 16 + ((l >> 4) * 4);
#pragma unroll
    for (int n = 0; n < 4; ++n) {
      int col = wn * 64 + n * 16 + (l & 15);
      float bv = b1e[col];
#pragma unroll
      for (int i = 0; i < 4; ++i) {
        float v = acc[m][n][i] + bv;
        Cs[(row + i) * BN + col] = f2bf(v / (1.f + __expf(-v)));
      }
    }
  }
  __syncthreads();
#pragma unroll
  for (int it = 0; it < 8; ++it) {
    int row = it * 16 + (t >> 4);
    int coff = (t & 15) * 8;
    *(ushort8*)(h + (size_t)(r0 + row) * FDIM + n0 + coff) = *(const ushort8*)(Cs + row * BN + coff);
  }
}

// ---------------- GEMM2 (swapped): y^T[hcol][slot] = w2t[hcol][:] . h[slot][:] ----------------
// A = w2t rows [128 hcol][64 f] (w2t: [E][H][F] bf16), B = h rows [128 slot][64 f]
__global__ __launch_bounds__(256) void k_gemm2(
    const unsigned short* __restrict__ h, const unsigned short* __restrict__ w2t,
    const float* __restrict__ b2, const int* __restrict__ list_tok,
    const float* __restrict__ list_wt, const int* __restrict__ counts,
    const int* __restrict__ off_pad, float* __restrict__ out) {
  __shared__ __align__(16) unsigned short smem[2 * BM * BK];
  unsigned short* As = smem;
  unsigned short* Bs = smem + BM * BK;

  int r0 = blockIdx.x * BM;            // slot block
  if (r0 >= off_pad[NEXP]) return;
  int e = 0;
#pragma unroll
  for (int i = 0; i < NEXP; ++i) if (r0 >= off_pad[i + 1]) e = i + 1;
  int base = off_pad[e], cnt = counts[e];
  int hc0 = blockIdx.y * BN;           // hcol block

  int t = threadIdx.x, l = t & 63, w = t >> 6;
  int wm = w >> 1, wn = w & 1;

  const unsigned short* ag[4];
  const unsigned short* bg[4];
  unsigned short* al[4];
  unsigned short* bl[4];
#pragma unroll
  for (int s = 0; s < 4; ++s) {
    int rl = w * 32 + s * 8 + (l >> 3);
    ag[s] = w2t + (size_t)e * HDIM * FDIM + (size_t)(hc0 + rl) * FDIM + (l & 7) * 8;
    al[s] = As + (w * 32 + s * 8) * BK;
    bg[s] = h + (size_t)(r0 + rl) * FDIM + (l & 7) * 8;
    bl[s] = Bs + (w * 32 + s * 8) * BK;
  }

  f32x4 acc[4][4];
#pragma unroll
  for (int m = 0; m < 4; ++m)
#pragma unroll
    for (int n = 0; n < 4; ++n) acc[m][n] = (f32x4){0.f, 0.f, 0.f, 0.f};

  for (int kt = 0; kt < FDIM / BK; ++kt) {
    __syncthreads();
#pragma unroll
    for (int s = 0; s < 4; ++s) {
      gload16(ag[s] + kt * BK, al[s]);
      gload16(bg[s] + kt * BK, bl[s]);
    }
    __syncthreads();
#pragma unroll
    for (int kh = 0; kh < 2; ++kh) {
      short8 af[4], bf[4];
#pragma unroll
      for (int m = 0; m < 4; ++m)
        af[m] = *(const short8*)(As + (wm * 64 + m * 16 + (l & 15)) * BK + kh * 32 + (l >> 4) * 8);
#pragma unroll
      for (int n = 0; n < 4; ++n)
        bf[n] = *(const short8*)(Bs + (wn * 64 + n * 16 + (l & 15)) * BK + kh * 32 + (l >> 4) * 8);
#pragma unroll
      for (int m = 0; m < 4; ++m)
#pragma unroll
        for (int n = 0; n < 4; ++n)
          acc[m][n] = __builtin_amdgcn_mfma_f32_16x16x32_bf16(af[m], bf[n], acc[m][n], 0, 0, 0);
    }
  }

  // epilogue: D[row=hcol][col=slot]; combine-weighted atomic scatter
  int tok_n[4]; float wt_n[4];
#pragma unroll
  for (int n = 0; n < 4; ++n) {
    int se = r0 - base + wn * 64 + n * 16 + (l & 15);
    bool val = se < cnt;
    tok_n[n] = val ? list_tok[e * T_TOK + se] : -1;
    wt_n[n]  = val ? list_wt[e * T_TOK + se] : 0.f;
  }
  const float* b2e = b2 + (size_t)e * HDIM + hc0;
#pragma unroll
  for (int m = 0; m < 4; ++m) {
#pragma unroll
    for (int i = 0; i < 4; ++i) {
      int hrow = wm * 64 + m * 16 + (l >> 4) * 4 + i;
      float bv = b2e[hrow];
#pragma unroll
      for (int n = 0; n < 4; ++n) {
        if (tok_n[n] >= 0)
          atomicAdd(out + (size_t)tok_n[n] * HDIM + hc0 + hrow, wt_n[n] * (acc[m][n][i] + bv));
      }
    }
  }
}

extern "C" void kernel_launch(void* const* d_in, const int* in_sizes, int n_in,
                              void* d_out, int out_size, void* d_ws, size_t ws_size,
                              hipStream_t stream) {
  const float* x  = (const float*)d_in[0];
  const float* gw = (const float*)d_in[1];
  const float* w1 = (const float*)d_in[2];
  const float* b1 = (const float*)d_in[3];
  const float* w2 = (const float*)d_in[4];
  const float* b2 = (const float*)d_in[5];
  float* out = (float*)d_out;

  char* ws = (char*)d_ws;
  size_t off = 0;
  unsigned short* xb = (unsigned short*)(ws + off); off += (size_t)T_TOK * HDIM * 2;
  int2*   eidx = (int2*)(ws + off);   off += (size_t)T_TOK * 8;
  float2* ewt  = (float2*)(ws + off); off += (size_t)T_TOK * 8;
  int*   list_tok = (int*)(ws + off);   off += (size_t)NEXP * T_TOK * 4;
  float* list_wt  = (float*)(ws + off); off += (size_t)NEXP * T_TOK * 4;
  int* counts  = (int*)(ws + off); off += 64;
  int* off_pad = (int*)(ws + off); off += 64;
  off = (off + 255) & ~(size_t)255;
  unsigned short* h = (unsigned short*)(ws + off);  off += (size_t)RCAP * FDIM * 2;
  unsigned short* wT = (unsigned short*)(ws + off); off += (size_t)NEXP * HDIM * FDIM * 2;
  if (ws_size < off) return;  // workspace too small -> fail loudly

  hipMemsetAsync(d_out, 0, (size_t)T_TOK * HDIM * 4, stream);
  k_convert_x<<<T_TOK * HDIM / 1024, 256, 0, stream>>>(x, xb);
  k_gate<<<T_TOK / 4, 256, 0, stream>>>(x, gw, eidx, ewt);
  k_compact<<<NEXP, 256, 0, stream>>>(eidx, ewt, list_tok, list_wt, counts);
  k_offsets<<<1, 64, 0, stream>>>(counts, off_pad);
  // w1 [E][H][F] f32 -> wT [E][F][H] bf16
  k_transp_cvt<<<dim3(FDIM / 64, HDIM / 64, NEXP), 256, 0, stream>>>(w1, wT, HDIM, FDIM);
  k_gemm1<<<dim3(FDIM / BN, RCAP / BM), 256, 0, stream>>>(xb, wT, b1, list_tok, counts, off_pad, h);
  // w2 [E][F][H] f32 -> wT [E][H][F] bf16 (reuse buffer after GEMM1)
  k_transp_cvt<<<dim3(HDIM / 64, FDIM / 64, NEXP), 256, 0, stream>>>(w2, wT, FDIM, HDIM);
  k_gemm2<<<dim3(RCAP / BM, HDIM / BN), 256, 0, stream>>>(h, wT, b2, list_tok, list_wt, counts, off_pad, out);
}